// Round 3
// baseline (51.898 us; speedup 1.0000x reference)
//
#include <hip/hip_runtime.h>

#define EPS 1e-10f

typedef float f32x4 __attribute__((ext_vector_type(4)));

// out[n] = exp( sum_f lw[f] * log(|iw[f]*x[n,f]| + EPS) ), N rows, F=64.
// Thread t handles float4 quad (t&15) of row (t>>4). 16 lanes per row.
// Non-temporal streaming loads/stores; 2x unrolled grid-stride loop.
__global__ __launch_bounds__(256) void pta_log_kernel(
    const float* __restrict__ x,
    const float* __restrict__ iw,
    const float* __restrict__ lw,
    float* __restrict__ out,
    int n_quads)  // = N * 16
{
    const int tid = blockIdx.x * blockDim.x + threadIdx.x;
    const int nthreads = gridDim.x * blockDim.x;   // multiple of 16
    const int quad = tid & 15;

    // loop-invariant per-thread weights (quad fixed across the stride loop)
    const f32x4 w4 = reinterpret_cast<const f32x4*>(iw)[quad];
    const f32x4 l4 = reinterpret_cast<const f32x4*>(lw)[quad];

    const f32x4* __restrict__ x4 = reinterpret_cast<const f32x4*>(x);

    int t = tid;
    // 2x unrolled main loop: two independent 16B loads in flight
    for (; t + nthreads < n_quads; t += 2 * nthreads) {
        const f32x4 xa = __builtin_nontemporal_load(&x4[t]);
        const f32x4 xb = __builtin_nontemporal_load(&x4[t + nthreads]);

        float sa, sb;
        sa = l4.x * __logf(fabsf(w4.x * xa.x) + EPS);
        sb = l4.x * __logf(fabsf(w4.x * xb.x) + EPS);
        sa = fmaf(l4.y, __logf(fabsf(w4.y * xa.y) + EPS), sa);
        sb = fmaf(l4.y, __logf(fabsf(w4.y * xb.y) + EPS), sb);
        sa = fmaf(l4.z, __logf(fabsf(w4.z * xa.z) + EPS), sa);
        sb = fmaf(l4.z, __logf(fabsf(w4.z * xb.z) + EPS), sb);
        sa = fmaf(l4.w, __logf(fabsf(w4.w * xa.w) + EPS), sa);
        sb = fmaf(l4.w, __logf(fabsf(w4.w * xb.w) + EPS), sb);

        sa += __shfl_xor(sa, 1);
        sb += __shfl_xor(sb, 1);
        sa += __shfl_xor(sa, 2);
        sb += __shfl_xor(sb, 2);
        sa += __shfl_xor(sa, 4);
        sb += __shfl_xor(sb, 4);
        sa += __shfl_xor(sa, 8);
        sb += __shfl_xor(sb, 8);

        if (quad == 0) {
            __builtin_nontemporal_store(__expf(sa), &out[t >> 4]);
            __builtin_nontemporal_store(__expf(sb), &out[(t + nthreads) >> 4]);
        }
    }
    // tail
    for (; t < n_quads; t += nthreads) {
        const f32x4 xv = __builtin_nontemporal_load(&x4[t]);
        float s;
        s = l4.x * __logf(fabsf(w4.x * xv.x) + EPS);
        s = fmaf(l4.y, __logf(fabsf(w4.y * xv.y) + EPS), s);
        s = fmaf(l4.z, __logf(fabsf(w4.z * xv.z) + EPS), s);
        s = fmaf(l4.w, __logf(fabsf(w4.w * xv.w) + EPS), s);
        s += __shfl_xor(s, 1);
        s += __shfl_xor(s, 2);
        s += __shfl_xor(s, 4);
        s += __shfl_xor(s, 8);
        if (quad == 0) __builtin_nontemporal_store(__expf(s), &out[t >> 4]);
    }
}

extern "C" void kernel_launch(void* const* d_in, const int* in_sizes, int n_in,
                              void* d_out, int out_size, void* d_ws, size_t ws_size,
                              hipStream_t stream) {
    const float* x  = (const float*)d_in[0];   // [N, 64] f32
    const float* iw = (const float*)d_in[1];   // [64] f32
    const float* lw = (const float*)d_in[2];   // [1, 64] f32 (flat 64)
    float* out = (float*)d_out;                // [N] f32

    const int N = in_sizes[0] / 64;
    const int n_quads = N * 16;

    const int block = 256;
    const int grid = 2048;

    pta_log_kernel<<<grid, block, 0, stream>>>(x, iw, lw, out, n_quads);
}

// Round 4
// 46.629 us; speedup vs baseline: 1.1130x; 1.1130x over previous
//
#include <hip/hip_runtime.h>

#define EPS 1e-10f

typedef float f32x4 __attribute__((ext_vector_type(4)));

// out[n] = exp( sum_f lw[f] * log(|iw[f]*x[n,f]| + EPS) ), N rows, F=64.
// Thread t handles float4 quad (t&15) of row (t>>4). 16 lanes per row.
// Plain (cached) loads/stores; 2x unrolled grid-stride loop for load ILP.
__global__ __launch_bounds__(256) void pta_log_kernel(
    const float* __restrict__ x,
    const float* __restrict__ iw,
    const float* __restrict__ lw,
    float* __restrict__ out,
    int n_quads)  // = N * 16
{
    const int tid = blockIdx.x * blockDim.x + threadIdx.x;
    const int nthreads = gridDim.x * blockDim.x;   // multiple of 16
    const int quad = tid & 15;

    // loop-invariant per-thread weights (quad fixed across the stride loop)
    const f32x4 w4 = reinterpret_cast<const f32x4*>(iw)[quad];
    const f32x4 l4 = reinterpret_cast<const f32x4*>(lw)[quad];

    const f32x4* __restrict__ x4 = reinterpret_cast<const f32x4*>(x);

    int t = tid;
    // 2x unrolled main loop: two independent 16B loads in flight
    for (; t + nthreads < n_quads; t += 2 * nthreads) {
        const f32x4 xa = x4[t];
        const f32x4 xb = x4[t + nthreads];

        float sa, sb;
        sa = l4.x * __logf(fabsf(w4.x * xa.x) + EPS);
        sb = l4.x * __logf(fabsf(w4.x * xb.x) + EPS);
        sa = fmaf(l4.y, __logf(fabsf(w4.y * xa.y) + EPS), sa);
        sb = fmaf(l4.y, __logf(fabsf(w4.y * xb.y) + EPS), sb);
        sa = fmaf(l4.z, __logf(fabsf(w4.z * xa.z) + EPS), sa);
        sb = fmaf(l4.z, __logf(fabsf(w4.z * xb.z) + EPS), sb);
        sa = fmaf(l4.w, __logf(fabsf(w4.w * xa.w) + EPS), sa);
        sb = fmaf(l4.w, __logf(fabsf(w4.w * xb.w) + EPS), sb);

        sa += __shfl_xor(sa, 1);
        sb += __shfl_xor(sb, 1);
        sa += __shfl_xor(sa, 2);
        sb += __shfl_xor(sb, 2);
        sa += __shfl_xor(sa, 4);
        sb += __shfl_xor(sb, 4);
        sa += __shfl_xor(sa, 8);
        sb += __shfl_xor(sb, 8);

        if (quad == 0) {
            out[t >> 4] = __expf(sa);
            out[(t + nthreads) >> 4] = __expf(sb);
        }
    }
    // tail
    for (; t < n_quads; t += nthreads) {
        const f32x4 xv = x4[t];
        float s;
        s = l4.x * __logf(fabsf(w4.x * xv.x) + EPS);
        s = fmaf(l4.y, __logf(fabsf(w4.y * xv.y) + EPS), s);
        s = fmaf(l4.z, __logf(fabsf(w4.z * xv.z) + EPS), s);
        s = fmaf(l4.w, __logf(fabsf(w4.w * xv.w) + EPS), s);
        s += __shfl_xor(s, 1);
        s += __shfl_xor(s, 2);
        s += __shfl_xor(s, 4);
        s += __shfl_xor(s, 8);
        if (quad == 0) out[t >> 4] = __expf(s);
    }
}

extern "C" void kernel_launch(void* const* d_in, const int* in_sizes, int n_in,
                              void* d_out, int out_size, void* d_ws, size_t ws_size,
                              hipStream_t stream) {
    const float* x  = (const float*)d_in[0];   // [N, 64] f32
    const float* iw = (const float*)d_in[1];   // [64] f32
    const float* lw = (const float*)d_in[2];   // [1, 64] f32 (flat 64)
    float* out = (float*)d_out;                // [N] f32

    const int N = in_sizes[0] / 64;
    const int n_quads = N * 16;

    const int block = 256;
    const int grid = 2048;

    pta_log_kernel<<<grid, block, 0, stream>>>(x, iw, lw, out, n_quads);
}

// Round 5
// 44.666 us; speedup vs baseline: 1.1619x; 1.0439x over previous
//
#include <hip/hip_runtime.h>

#define EPS 1e-10f

// out[n] = exp( sum_f lw[f] * log(|iw[f]*x[n,f]| + EPS) ), N rows, F=64.
// Thread t handles float4 quad (t&15) of row (t>>4). 16 lanes per row,
// 4 rows per wave iteration. Coalesced 16B/lane loads.
//
// R1 structure (proven 44.58 us = 5.83 TB/s effective, ~93% of measured
// achievable HBM BW). R3's non-temporal variant regressed (-16%), R4's
// 2x unroll regressed (-4.6%): the simple 1-load/iter grid-stride loop is
// already optimally pipelined by the compiler; nt bypass only hurts.
__global__ __launch_bounds__(256) void pta_log_kernel(
    const float* __restrict__ x,
    const float* __restrict__ iw,
    const float* __restrict__ lw,
    float* __restrict__ out,
    int n_quads)  // = N * 16
{
    const int tid = blockIdx.x * blockDim.x + threadIdx.x;
    const int nthreads = gridDim.x * blockDim.x;   // multiple of 16
    const int quad = tid & 15;

    // loop-invariant per-thread weights (quad is fixed across the stride loop)
    const float4 w4 = reinterpret_cast<const float4*>(iw)[quad];
    const float4 l4 = reinterpret_cast<const float4*>(lw)[quad];

    for (int t = tid; t < n_quads; t += nthreads) {
        const float4 xv = reinterpret_cast<const float4*>(x)[t];

        float s;
        s  = l4.x * __logf(fabsf(w4.x * xv.x) + EPS);
        s  = fmaf(l4.y, __logf(fabsf(w4.y * xv.y) + EPS), s);
        s  = fmaf(l4.z, __logf(fabsf(w4.z * xv.z) + EPS), s);
        s  = fmaf(l4.w, __logf(fabsf(w4.w * xv.w) + EPS), s);

        // reduce across the 16 lanes of this row (groups aligned in wave64)
        s += __shfl_xor(s, 1);
        s += __shfl_xor(s, 2);
        s += __shfl_xor(s, 4);
        s += __shfl_xor(s, 8);

        if (quad == 0) out[t >> 4] = __expf(s);
    }
}

extern "C" void kernel_launch(void* const* d_in, const int* in_sizes, int n_in,
                              void* d_out, int out_size, void* d_ws, size_t ws_size,
                              hipStream_t stream) {
    const float* x  = (const float*)d_in[0];   // [N, 64] f32
    const float* iw = (const float*)d_in[1];   // [64] f32
    const float* lw = (const float*)d_in[2];   // [1, 64] f32 (flat 64)
    float* out = (float*)d_out;                // [N] f32

    const int N = in_sizes[0] / 64;
    const int n_quads = N * 16;

    const int block = 256;
    const int grid = 2048;  // 8 blocks/CU -> 32 waves/CU, max occupancy

    pta_log_kernel<<<grid, block, 0, stream>>>(x, iw, lw, out, n_quads);
}